// Round 5
// baseline (128.956 us; speedup 1.0000x reference)
//
#include <hip/hip_runtime.h>
#include <stdint.h>

#define B_  4096
#define F_  512
#define T_  2048
#define D_  4
#define M_  (T_ * D_)   // 8192 GEMM-M (trees*dims)
#define KC_ (F_ / 8)    // 64 16-byte k-chunks per row
#define TAU 0.2018004745467103f

typedef __attribute__((ext_vector_type(8)))  short bf16x8;
typedef __attribute__((ext_vector_type(16))) float f32x16;

static __device__ __forceinline__ unsigned short f2bf(float f) {
  union { float f; uint32_t u; } v; v.f = f;
  uint32_t r = v.u + 0x7fffu + ((v.u >> 16) & 1u);  // RNE
  return (unsigned short)(r >> 16);
}
static __device__ __forceinline__ uint32_t pk2(float a, float b) {
  return ((uint32_t)f2bf(b) << 16) | f2bf(a);
}

// ---------------------------------------------------------------------------
// Prep v2: fully-coalesced global IO via LDS transpose (XOR swizzle).
//  blocks [0,256):    x (B,F) fp32 -> xbF frag-major; 16 rows/block.
//  blocks [256,768):  softmax rows -> wbF frag-major; 16 rows/block,
//                     row held in registers (single pass), same math as v1
//                     (max-subtract + RNE) so values are bit-comparable.
// Cell (kc,row) stored in LDS at slot row^(kc&15) -> write-in ~4-way bank
// aliasing, read-out conflict-free, and global writes become contiguous
// 256B-per-16-lane-group segments (coalescer is order-agnostic).
// ---------------------------------------------------------------------------
__global__ __launch_bounds__(256) void prep(
    const float* __restrict__ x, const float* __restrict__ logits,
    unsigned short* __restrict__ xbF, unsigned short* __restrict__ wbF) {
  __shared__ __align__(16) char sm[16384];
  const int tid = threadIdx.x;
  if (blockIdx.x < 256) {
    const int r0 = blockIdx.x * 16;
    const float4* x4 = (const float4*)x;
    #pragma unroll
    for (int p = 0; p < 8; ++p) {
      int idx = p * 256 + tid;
      int row = idx >> 7, col4 = idx & 127;
      int kc = col4 >> 1, half = col4 & 1;
      float4 f = x4[(size_t)(r0 + row) * 128 + col4];
      uint2 u = make_uint2(pk2(f.x, f.y), pk2(f.z, f.w));
      *(uint2*)(sm + (kc * 16 + (row ^ (kc & 15))) * 16 + half * 8) = u;
    }
    __syncthreads();
    const int w = tid >> 6, l = tid & 63;
    #pragma unroll
    for (int i = 0; i < 4; ++i) {
      int kc = w * 16 + i * 4 + (l >> 4);
      int slot = l & 15;
      int row = slot ^ (kc & 15);
      bf16x8 v = *(const bf16x8*)(sm + (kc * 16 + slot) * 16);
      *(bf16x8*)(xbF + ((size_t)kc * B_ + r0 + row) * 8) = v;
    }
  } else {
    const int m0r = (blockIdx.x - 256) * 16;
    const int row = tid >> 4, s = tid & 15;   // 16 lanes per logits row
    const float* src = logits + (size_t)(m0r + row) * F_;
    float4 a[8];
    #pragma unroll
    for (int j = 0; j < 8; ++j)
      a[j] = *(const float4*)(src + (s + 16 * j) * 4);
    float mx = fmaxf(fmaxf(a[0].x, a[0].y), fmaxf(a[0].z, a[0].w));
    #pragma unroll
    for (int j = 1; j < 8; ++j)
      mx = fmaxf(mx, fmaxf(fmaxf(a[j].x, a[j].y), fmaxf(a[j].z, a[j].w)));
    #pragma unroll
    for (int msk = 1; msk <= 8; msk <<= 1)
      mx = fmaxf(mx, __shfl_xor(mx, msk, 64));
    float sum = 0.0f;
    #pragma unroll
    for (int j = 0; j < 8; ++j) {
      a[j].x = __expf(a[j].x - mx); a[j].y = __expf(a[j].y - mx);
      a[j].z = __expf(a[j].z - mx); a[j].w = __expf(a[j].w - mx);
      sum += (a[j].x + a[j].y) + (a[j].z + a[j].w);
    }
    #pragma unroll
    for (int msk = 1; msk <= 8; msk <<= 1)
      sum += __shfl_xor(sum, msk, 64);
    float inv = 1.0f / sum;
    #pragma unroll
    for (int j = 0; j < 8; ++j) {
      int kc = 8 * j + (s >> 1), h = s & 1;
      uint2 u = make_uint2(pk2(a[j].x * inv, a[j].y * inv),
                           pk2(a[j].z * inv, a[j].w * inv));
      *(uint2*)(sm + (kc * 16 + (row ^ (kc & 15))) * 16 + h * 8) = u;
    }
    __syncthreads();
    const int w = tid >> 6, l = tid & 63;
    #pragma unroll
    for (int i = 0; i < 4; ++i) {
      int kc = w * 16 + i * 4 + (l >> 4);
      int slot = l & 15;
      int row2 = slot ^ (kc & 15);
      bf16x8 v = *(const bf16x8*)(sm + (kc * 16 + slot) * 16);
      *(bf16x8*)(wbF + ((size_t)kc * M_ + m0r + row2) * 8) = v;
    }
  }
}

// ---------------------------------------------------------------------------
// Round-5 GEMM: R2's tile/occupancy (256x128, 4 waves 2x2, wave 128x64,
// 2 blocks/CU) but ONE serial chain per K-tile instead of four.
// Round-4 post-mortem: the wall is (lgkm wait + barrier reconvergence) x
// chain count -- R2 paid 64 chains/block each covering only 8 MFMAs; m201
// amortizes chains over K=4096, we can't at K=512, so cut the count: per
// tile a single {VMCNT(6); s_barrier; stage(t+2); 12 ds_read; lgkm0;
// 16 MFMA} sequence = 16 barriers/block (was 64), 16 lgkm waits (was 32).
// Triple-buffered BK=32 (3 x 24KB = 72KB -> still 2 blocks/CU); stage
// distance 2 full tiles so VMCNT(6) waits on loads issued ~2000cy earlier
// (>> L2 latency ~200-500) -> effectively free. t==15 uses VMCNT(0)
// (its loads are only guaranteed by a full drain).
// Buffer-rotation safety: stage(t+2) targets buf[(t+2)%3] whose readers
// (tile t-1) completed their lgkm0 before this tile's barrier; readers of
// buf[t%3] finish before the t+1 barrier, before stage(t+3) touches it.
// ---------------------------------------------------------------------------
#define SBAR()  do { __builtin_amdgcn_sched_barrier(0); \
                     __builtin_amdgcn_s_barrier(); \
                     __builtin_amdgcn_sched_barrier(0); } while (0)
#define LGKM0() do { asm volatile("s_waitcnt lgkmcnt(0)" ::: "memory"); \
                     __builtin_amdgcn_sched_barrier(0); } while (0)
#define VMCNT(n) do { asm volatile("s_waitcnt vmcnt(" #n ")" ::: "memory"); \
                      __builtin_amdgcn_sched_barrier(0); } while (0)

__global__ __launch_bounds__(256, 2) void odst_mfma(
    const unsigned short* __restrict__ wbF,  // frag-major [KC][M] 16B cells
    const unsigned short* __restrict__ xbF,  // frag-major [KC][B] 16B cells
    const float* __restrict__ thr,           // [T][4]
    const float* __restrict__ leaf,          // [T][16]
    float* __restrict__ out) {               // [B][T]
  __shared__ __align__(16) char smem[73728];

  const int tid  = threadIdx.x;
  const int lane = tid & 63, wid = tid >> 6;   // 4 waves
  const int wm = wid >> 1, wn = wid & 1;       // 2 (m) x 2 (n)
  const int col = lane & 31, hi = lane >> 5;
  const int m0 = blockIdx.x * 256;             // m fast: neighbors share B
  const int n0 = blockIdx.y * 128;

  // wave `wid` stages kc slot `wid` of each BK=32 tile (global kc = t*4+wid)
  const unsigned short* gA = wbF + ((size_t)wid * M_ + m0 + lane) * 8;
  const unsigned short* gB = xbF + ((size_t)wid * B_ + n0 + lane) * 8;

  auto stage = [&](int t) {                    // 6 x 1KB wave-chunks
    char* base = smem + (t % 3) * 24576;
    #pragma unroll
    for (int j = 0; j < 4; ++j)
      __builtin_amdgcn_global_load_lds(
          (const __attribute__((address_space(1))) uint32_t*)(
              gA + ((size_t)t * 4 * M_ + j * 64) * 8),
          (__attribute__((address_space(3))) uint32_t*)(
              base + (wid * 256 + j * 64) * 16),
          16, 0, 0);
    #pragma unroll
    for (int j = 0; j < 2; ++j)
      __builtin_amdgcn_global_load_lds(
          (const __attribute__((address_space(1))) uint32_t*)(
              gB + ((size_t)t * 4 * B_ + j * 64) * 8),
          (__attribute__((address_space(3))) uint32_t*)(
              base + 16384 + (wid * 128 + j * 64) * 16),
          16, 0, 0);
  };

  f32x16 acc[4][2] = {};

  stage(0); stage(1);

  #pragma unroll
  for (int t = 0; t < 16; ++t) {               // K = 16 tiles x BK=32
    if (t == 15) { VMCNT(0); } else { VMCNT(6); }  // tile t resident
    SBAR();
    if (t < 14) stage(t + 2);                  // 2-tile-ahead prefetch
    const char* base = smem + (t % 3) * 24576;
    bf16x8 a[4][2], bb[2][2];
    #pragma unroll
    for (int ks = 0; ks < 2; ++ks) {
      #pragma unroll
      for (int mf = 0; mf < 4; ++mf)
        a[mf][ks] = *(const bf16x8*)(base +
            ((2 * ks + hi) * 256 + wm * 128 + mf * 32 + col) * 16);
      #pragma unroll
      for (int nf = 0; nf < 2; ++nf)
        bb[nf][ks] = *(const bf16x8*)(base + 16384 +
            ((2 * ks + hi) * 128 + wn * 64 + nf * 32 + col) * 16);
    }
    LGKM0();
    __builtin_amdgcn_s_setprio(1);
    #pragma unroll
    for (int ks = 0; ks < 2; ++ks)
      #pragma unroll
      for (int mf = 0; mf < 4; ++mf)
        #pragma unroll
        for (int nf = 0; nf < 2; ++nf)
          acc[mf][nf] = __builtin_amdgcn_mfma_f32_32x32x16_bf16(
              a[mf][ks], bb[nf][ks], acc[mf][nf], 0, 0, 0);
    __builtin_amdgcn_s_setprio(0);
  }

  __syncthreads();  // all frag reads done; LDS reusable for epilogue

  // ---- fused epilogue: C-layout n=col, d=reg&3, tree-in-frag=2g+hi ----
  float* eb = (float*)smem;                  // [128 batch][68] floats
  const float inv_tau = 1.0f / TAU;
  const int t0 = m0 >> 2;                    // 64 trees per block
  #pragma unroll
  for (int af = 0; af < 4; ++af) {
    #pragma unroll
    for (int g = 0; g < 4; ++g) {
      int tl = wm * 32 + af * 8 + 2 * g + hi;
      int tg = t0 + tl;
      float4 th  = *(const float4*)(thr + tg * 4);
      float4 lf0 = *(const float4*)(leaf + tg * 16);
      float4 lf1 = *(const float4*)(leaf + tg * 16 + 4);
      float4 lf2 = *(const float4*)(leaf + tg * 16 + 8);
      float4 lf3 = *(const float4*)(leaf + tg * 16 + 12);
      float c2x = th.x * inv_tau, c2y = th.y * inv_tau,
            c2z = th.z * inv_tau, c2w = th.w * inv_tau;
      #pragma unroll
      for (int nf = 0; nf < 2; ++nf) {
        float p0 = __builtin_amdgcn_rcpf(1.0f + __expf(fmaf(acc[af][nf][g * 4 + 0], -inv_tau, c2x)));
        float p1 = __builtin_amdgcn_rcpf(1.0f + __expf(fmaf(acc[af][nf][g * 4 + 1], -inv_tau, c2y)));
        float p2 = __builtin_amdgcn_rcpf(1.0f + __expf(fmaf(acc[af][nf][g * 4 + 2], -inv_tau, c2z)));
        float p3 = __builtin_amdgcn_rcpf(1.0f + __expf(fmaf(acc[af][nf][g * 4 + 3], -inv_tau, c2w)));
        float q0 = 1.0f - p0, q1 = 1.0f - p1, q2 = 1.0f - p2, q3 = 1.0f - p3;
        float A0 = lf0.x * q0 + lf0.y * p0;
        float A1 = lf0.z * q0 + lf0.w * p0;
        float A2 = lf1.x * q0 + lf1.y * p0;
        float A3 = lf1.z * q0 + lf1.w * p0;
        float A4 = lf2.x * q0 + lf2.y * p0;
        float A5 = lf2.z * q0 + lf2.w * p0;
        float A6 = lf3.x * q0 + lf3.y * p0;
        float A7 = lf3.z * q0 + lf3.w * p0;
        float B0 = A0 * q1 + A1 * p1;
        float B1 = A2 * q1 + A3 * p1;
        float B2 = A4 * q1 + A5 * p1;
        float B3 = A6 * q1 + A7 * p1;
        float C0 = B0 * q2 + B1 * p2;
        float C1 = B2 * q2 + B3 * p2;
        float o  = C0 * q3 + C1 * p3;
        int bl = wn * 64 + nf * 32 + col;    // batch within block [0,128)
        eb[bl * 68 + tl] = o;
      }
    }
  }
  __syncthreads();

  // coalesced store: 128 batch rows x 64 trees, float4 per thread-slot
  #pragma unroll
  for (int pass = 0; pass < 8; ++pass) {
    int row = pass * 16 + (tid >> 4);
    int s   = tid & 15;
    float4 v = *(const float4*)(eb + row * 68 + s * 4);
    *(float4*)(out + (size_t)(n0 + row) * T_ + t0 + s * 4) = v;
  }
}

extern "C" void kernel_launch(void* const* d_in, const int* in_sizes, int n_in,
                              void* d_out, int out_size, void* d_ws, size_t ws_size,
                              hipStream_t stream) {
  const float* x    = (const float*)d_in[0];  // (B, F)
  const float* fl   = (const float*)d_in[1];  // (T, D, F)
  const float* thr  = (const float*)d_in[2];  // (T, D)
  const float* leaf = (const float*)d_in[3];  // (T, 16)
  float* out = (float*)d_out;                 // (B, T)

  unsigned short* wbF = (unsigned short*)d_ws;                                  // 8 MB
  unsigned short* xbF = (unsigned short*)((char*)d_ws + (size_t)KC_ * M_ * 16); // 4 MB

  prep<<<dim3(768), dim3(256), 0, stream>>>(x, fl, xbF, wbF);
  odst_mfma<<<dim3(M_ / 256, B_ / 128), dim3(256), 0, stream>>>(wbF, xbF, thr, leaf, out);
}

// Round 6
// 125.612 us; speedup vs baseline: 1.0266x; 1.0266x over previous
//
#include <hip/hip_runtime.h>
#include <stdint.h>

#define B_  4096
#define F_  512
#define T_  2048
#define D_  4
#define M_  (T_ * D_)   // 8192 GEMM-M (trees*dims)
#define KC_ (F_ / 8)    // 64 16-byte k-chunks per row
#define TAU 0.2018004745467103f

typedef __attribute__((ext_vector_type(8)))  short bf16x8;
typedef __attribute__((ext_vector_type(16))) float f32x16;

static __device__ __forceinline__ unsigned short f2bf(float f) {
  union { float f; uint32_t u; } v; v.f = f;
  uint32_t r = v.u + 0x7fffu + ((v.u >> 16) & 1u);  // RNE
  return (unsigned short)(r >> 16);
}
static __device__ __forceinline__ uint32_t pk2(float a, float b) {
  return ((uint32_t)f2bf(b) << 16) | f2bf(a);
}

// ---------------------------------------------------------------------------
// Prep v2 (verified round 5, -22us vs v1): fully-coalesced global IO via LDS
// transpose (XOR swizzle). Kept byte-identical.
// ---------------------------------------------------------------------------
__global__ __launch_bounds__(256) void prep(
    const float* __restrict__ x, const float* __restrict__ logits,
    unsigned short* __restrict__ xbF, unsigned short* __restrict__ wbF) {
  __shared__ __align__(16) char sm[16384];
  const int tid = threadIdx.x;
  if (blockIdx.x < 256) {
    const int r0 = blockIdx.x * 16;
    const float4* x4 = (const float4*)x;
    #pragma unroll
    for (int p = 0; p < 8; ++p) {
      int idx = p * 256 + tid;
      int row = idx >> 7, col4 = idx & 127;
      int kc = col4 >> 1, half = col4 & 1;
      float4 f = x4[(size_t)(r0 + row) * 128 + col4];
      uint2 u = make_uint2(pk2(f.x, f.y), pk2(f.z, f.w));
      *(uint2*)(sm + (kc * 16 + (row ^ (kc & 15))) * 16 + half * 8) = u;
    }
    __syncthreads();
    const int w = tid >> 6, l = tid & 63;
    #pragma unroll
    for (int i = 0; i < 4; ++i) {
      int kc = w * 16 + i * 4 + (l >> 4);
      int slot = l & 15;
      int row = slot ^ (kc & 15);
      bf16x8 v = *(const bf16x8*)(sm + (kc * 16 + slot) * 16);
      *(bf16x8*)(xbF + ((size_t)kc * B_ + r0 + row) * 8) = v;
    }
  } else {
    const int m0r = (blockIdx.x - 256) * 16;
    const int row = tid >> 4, s = tid & 15;   // 16 lanes per logits row
    const float* src = logits + (size_t)(m0r + row) * F_;
    float4 a[8];
    #pragma unroll
    for (int j = 0; j < 8; ++j)
      a[j] = *(const float4*)(src + (s + 16 * j) * 4);
    float mx = fmaxf(fmaxf(a[0].x, a[0].y), fmaxf(a[0].z, a[0].w));
    #pragma unroll
    for (int j = 1; j < 8; ++j)
      mx = fmaxf(mx, fmaxf(fmaxf(a[j].x, a[j].y), fmaxf(a[j].z, a[j].w)));
    #pragma unroll
    for (int msk = 1; msk <= 8; msk <<= 1)
      mx = fmaxf(mx, __shfl_xor(mx, msk, 64));
    float sum = 0.0f;
    #pragma unroll
    for (int j = 0; j < 8; ++j) {
      a[j].x = __expf(a[j].x - mx); a[j].y = __expf(a[j].y - mx);
      a[j].z = __expf(a[j].z - mx); a[j].w = __expf(a[j].w - mx);
      sum += (a[j].x + a[j].y) + (a[j].z + a[j].w);
    }
    #pragma unroll
    for (int msk = 1; msk <= 8; msk <<= 1)
      sum += __shfl_xor(sum, msk, 64);
    float inv = 1.0f / sum;
    #pragma unroll
    for (int j = 0; j < 8; ++j) {
      int kc = 8 * j + (s >> 1), h = s & 1;
      uint2 u = make_uint2(pk2(a[j].x * inv, a[j].y * inv),
                           pk2(a[j].z * inv, a[j].w * inv));
      *(uint2*)(sm + (kc * 16 + (row ^ (kc & 15))) * 16 + h * 8) = u;
    }
    __syncthreads();
    const int w = tid >> 6, l = tid & 63;
    #pragma unroll
    for (int i = 0; i < 4; ++i) {
      int kc = w * 16 + i * 4 + (l >> 4);
      int slot = l & 15;
      int row2 = slot ^ (kc & 15);
      bf16x8 v = *(const bf16x8*)(sm + (kc * 16 + slot) * 16);
      *(bf16x8*)(wbF + ((size_t)kc * M_ + m0r + row2) * 8) = v;
    }
  }
}

// ---------------------------------------------------------------------------
// Round-6 GEMM: occupancy-first. Round-5 post-mortem found the real cap:
// one 32x32x16 MFMA = ~32 SIMD-cycles, and every prior variant's acc[4][2]
// (128 AGPR) + ~92 VGPR = 220 unified regs -> 2 waves/SIMD, which cannot
// hide the per-tile serial chain (~2700 stalled cycles per 3750-cycle tile
// period -> the invariant 27% MfmaUtil). Fix: wave tile 64x64 -> acc[2][2]
// = 64 regs; launch_bounds(256,3) caps total at 170 -> 3 waves/SIMD =
// 3 blocks/CU (m97's proven operating point).
// Block 128x128, 4 waves (2x2), BK=32 double-buffered = 32KB LDS.
// Per tile: {stage(t+1) 4 loads; VMCNT(4); SBAR; 8 ds_read_b128; LGKM0;
// 8 MFMA; SBAR} - R2's proven rhythm, counted vmcnt (loads issued one full
// tile-period earlier; L2 latency covered; other resident blocks cover the
// rest). Frag-major [kc][128 row] 16B cells: conflict-free b128 reads +
// linear 1KB global_load_lds chunks. No setprio (m190: null for this class).
// Grid 64(m) x 32(n), m fast -> consecutive blocks share the B strip.
// ---------------------------------------------------------------------------
#define SBAR()  do { __builtin_amdgcn_sched_barrier(0); \
                     __builtin_amdgcn_s_barrier(); \
                     __builtin_amdgcn_sched_barrier(0); } while (0)
#define LGKM0() do { asm volatile("s_waitcnt lgkmcnt(0)" ::: "memory"); \
                     __builtin_amdgcn_sched_barrier(0); } while (0)
#define VMCNT(n) do { asm volatile("s_waitcnt vmcnt(" #n ")" ::: "memory"); \
                      __builtin_amdgcn_sched_barrier(0); } while (0)

__global__ __launch_bounds__(256, 3) void odst_mfma(
    const unsigned short* __restrict__ wbF,  // frag-major [KC][M] 16B cells
    const unsigned short* __restrict__ xbF,  // frag-major [KC][B] 16B cells
    const float* __restrict__ thr,           // [T][4]
    const float* __restrict__ leaf,          // [T][16]
    float* __restrict__ out) {               // [B][T]
  __shared__ __align__(16) char smem[32768];

  const int tid  = threadIdx.x;
  const int lane = tid & 63, wid = tid >> 6;   // 4 waves
  const int wm = wid >> 1, wn = wid & 1;       // 2 (m) x 2 (n)
  const int col = lane & 31, hi = lane >> 5;
  const int m0 = blockIdx.x * 128;             // m fast: neighbors share B
  const int n0 = blockIdx.y * 128;

  // wave `wid` stages kc slot `wid` of each BK=32 tile (global kc = t*4+wid)
  const unsigned short* gA = wbF + ((size_t)wid * M_ + m0 + lane) * 8;
  const unsigned short* gB = xbF + ((size_t)wid * B_ + n0 + lane) * 8;

  auto stage = [&](int t) {                    // 4 x 1KB wave-chunks
    char* base = smem + (t & 1) * 16384;
    #pragma unroll
    for (int j = 0; j < 2; ++j) {
      __builtin_amdgcn_global_load_lds(
          (const __attribute__((address_space(1))) uint32_t*)(
              gA + ((size_t)t * 4 * M_ + j * 64) * 8),
          (__attribute__((address_space(3))) uint32_t*)(
              base + (wid * 128 + j * 64) * 16),
          16, 0, 0);
      __builtin_amdgcn_global_load_lds(
          (const __attribute__((address_space(1))) uint32_t*)(
              gB + ((size_t)t * 4 * B_ + j * 64) * 8),
          (__attribute__((address_space(3))) uint32_t*)(
              base + 8192 + (wid * 128 + j * 64) * 16),
          16, 0, 0);
    }
  };

  f32x16 acc[2][2] = {};

  stage(0);

  #pragma unroll
  for (int t = 0; t < 16; ++t) {               // K = 16 tiles x BK=32
    if (t < 15) { stage(t + 1); VMCNT(4); }    // tile t resident (4 in flight)
    else        { VMCNT(0); }
    SBAR();                                    // all waves' stages visible
    const char* base = smem + (t & 1) * 16384;
    bf16x8 a[2][2], b[2][2];
    #pragma unroll
    for (int ks = 0; ks < 2; ++ks) {
      #pragma unroll
      for (int mf = 0; mf < 2; ++mf)
        a[mf][ks] = *(const bf16x8*)(base +
            ((2 * ks + hi) * 128 + wm * 64 + mf * 32 + col) * 16);
      #pragma unroll
      for (int nf = 0; nf < 2; ++nf)
        b[nf][ks] = *(const bf16x8*)(base + 8192 +
            ((2 * ks + hi) * 128 + wn * 64 + nf * 32 + col) * 16);
    }
    LGKM0();
    #pragma unroll
    for (int ks = 0; ks < 2; ++ks)
      #pragma unroll
      for (int mf = 0; mf < 2; ++mf)
        #pragma unroll
        for (int nf = 0; nf < 2; ++nf)
          acc[mf][nf] = __builtin_amdgcn_mfma_f32_32x32x16_bf16(
              a[mf][ks], b[nf][ks], acc[mf][nf], 0, 0, 0);
    SBAR();                                    // reads done before overwrite
  }

  __syncthreads();  // LDS reusable for epilogue

  // ---- fused epilogue: C-layout n=col, d=reg&3, tree-in-frag=2g+hi ----
  float* eb = (float*)smem;                  // [128 batch][34] floats
  const float inv_tau = 1.0f / TAU;
  const int t0 = m0 >> 2;                    // 32 trees per block
  #pragma unroll
  for (int mf = 0; mf < 2; ++mf) {
    #pragma unroll
    for (int g = 0; g < 4; ++g) {
      int tl = wm * 16 + mf * 8 + 2 * g + hi;
      int tg = t0 + tl;
      float4 th  = *(const float4*)(thr + tg * 4);
      float4 lf0 = *(const float4*)(leaf + tg * 16);
      float4 lf1 = *(const float4*)(leaf + tg * 16 + 4);
      float4 lf2 = *(const float4*)(leaf + tg * 16 + 8);
      float4 lf3 = *(const float4*)(leaf + tg * 16 + 12);
      float c2x = th.x * inv_tau, c2y = th.y * inv_tau,
            c2z = th.z * inv_tau, c2w = th.w * inv_tau;
      #pragma unroll
      for (int nf = 0; nf < 2; ++nf) {
        float p0 = __builtin_amdgcn_rcpf(1.0f + __expf(fmaf(acc[mf][nf][g * 4 + 0], -inv_tau, c2x)));
        float p1 = __builtin_amdgcn_rcpf(1.0f + __expf(fmaf(acc[mf][nf][g * 4 + 1], -inv_tau, c2y)));
        float p2 = __builtin_amdgcn_rcpf(1.0f + __expf(fmaf(acc[mf][nf][g * 4 + 2], -inv_tau, c2z)));
        float p3 = __builtin_amdgcn_rcpf(1.0f + __expf(fmaf(acc[mf][nf][g * 4 + 3], -inv_tau, c2w)));
        float q0 = 1.0f - p0, q1 = 1.0f - p1, q2 = 1.0f - p2, q3 = 1.0f - p3;
        float A0 = lf0.x * q0 + lf0.y * p0;
        float A1 = lf0.z * q0 + lf0.w * p0;
        float A2 = lf1.x * q0 + lf1.y * p0;
        float A3 = lf1.z * q0 + lf1.w * p0;
        float A4 = lf2.x * q0 + lf2.y * p0;
        float A5 = lf2.z * q0 + lf2.w * p0;
        float A6 = lf3.x * q0 + lf3.y * p0;
        float A7 = lf3.z * q0 + lf3.w * p0;
        float B0 = A0 * q1 + A1 * p1;
        float B1 = A2 * q1 + A3 * p1;
        float B2 = A4 * q1 + A5 * p1;
        float B3 = A6 * q1 + A7 * p1;
        float C0 = B0 * q2 + B1 * p2;
        float C1 = B2 * q2 + B3 * p2;
        float o  = C0 * q3 + C1 * p3;
        int bl = wn * 64 + nf * 32 + col;    // batch within block [0,128)
        eb[bl * 34 + tl] = o;                // stride 34: 2-way (free)
      }
    }
  }
  __syncthreads();

  // coalesced store: 128 batch rows x 32 trees, float4 per thread-slot
  #pragma unroll
  for (int pass = 0; pass < 4; ++pass) {
    int row = pass * 32 + (tid >> 3);
    int s   = tid & 7;
    const float* p = eb + row * 34 + s * 4;
    float2 v0 = *(const float2*)p;
    float2 v1 = *(const float2*)(p + 2);
    float4 v;
    v.x = v0.x; v.y = v0.y; v.z = v1.x; v.w = v1.y;
    *(float4*)(out + (size_t)(n0 + row) * T_ + t0 + s * 4) = v;
  }
}

extern "C" void kernel_launch(void* const* d_in, const int* in_sizes, int n_in,
                              void* d_out, int out_size, void* d_ws, size_t ws_size,
                              hipStream_t stream) {
  const float* x    = (const float*)d_in[0];  // (B, F)
  const float* fl   = (const float*)d_in[1];  // (T, D, F)
  const float* thr  = (const float*)d_in[2];  // (T, D)
  const float* leaf = (const float*)d_in[3];  // (T, 16)
  float* out = (float*)d_out;                 // (B, T)

  unsigned short* wbF = (unsigned short*)d_ws;                                  // 8 MB
  unsigned short* xbF = (unsigned short*)((char*)d_ws + (size_t)KC_ * M_ * 16); // 4 MB

  prep<<<dim3(768), dim3(256), 0, stream>>>(x, fl, xbF, wbF);
  odst_mfma<<<dim3(M_ / 128, B_ / 128), dim3(256), 0, stream>>>(wbF, xbF, thr, leaf, out);
}